// Round 6
// baseline (1231.493 us; speedup 1.0000x reference)
//
#include <hip/hip_runtime.h>
#include <hip/hip_fp16.h>
#include <hip/hip_cooperative_groups.h>

namespace cg = cooperative_groups;

// Clang native vector types — required by __builtin_nontemporal_* (HIP's
// float4/int4 are classes, which the builtin rejects).
typedef float vf4 __attribute__((ext_vector_type(4)));
typedef int   vi4 __attribute__((ext_vector_type(4)));

// Packed node record: path-segment sum s and jump pointer p in 8 bytes,
// so each random gather touches exactly one cache line.
struct SP { float s; int p; };

__device__ __forceinline__ SP ldSP(const SP* __restrict__ ptr) {
    float2 v = *reinterpret_cast<const float2*>(ptr);
    SP r; r.s = v.x; r.p = __float_as_int(v.y);
    return r;
}
__device__ __forceinline__ void stSP(SP* __restrict__ ptr, float s, int p) {
    float2 v; v.x = s; v.y = __int_as_float(p);
    *reinterpret_cast<float2*>(ptr) = v;
}

#define TPREF 524288    // prefix: 4 MB of buf, chase-to-root region
#define SEG   1048576   // pixel-gather segment split (2 MB fp16 halves of y16)

__global__ __launch_bounds__(256, 8) void k_fused(
    const float* __restrict__ attrs,
    const float* __restrict__ weight,
    const float* __restrict__ bias,
    const float* __restrict__ levels,
    const int*   __restrict__ parent,
    const int*   __restrict__ pix,
    float*       __restrict__ out,
    SP*          __restrict__ buf,
    float*       __restrict__ yAll,
    __half*      __restrict__ y16,
    __half*      __restrict__ lev16,
    int N, int M)
{
    cg::grid_group grid = cg::this_grid();
    const int tid  = blockIdx.x * blockDim.x + threadIdx.x;
    const int nthr = gridDim.x * blockDim.x;

    // P0: levels -> fp16 (4 MB, L2-fits) so P1's random parent-level gathers hit L2.
    for (int i = tid; i < N; i += nthr)
        lev16[i] = __float2half(levels[i]);
    grid.sync();

    // P1: contrib[i] = sigmoid(attrs[i]·w+b) * (lev[i] - lev[parent]); root = level[0].
    {
        const float w0=weight[0],w1=weight[1],w2=weight[2],w3=weight[3];
        const float w4=weight[4],w5=weight[5],w6=weight[6],w7=weight[7];
        const float b = bias[0];
        const vf4* a4 = reinterpret_cast<const vf4*>(attrs);
        for (int i = tid; i < N; i += nthr) {
            vf4 a0 = __builtin_nontemporal_load(&a4[2*(size_t)i]);
            vf4 a1 = __builtin_nontemporal_load(&a4[2*(size_t)i+1]);
            float x = a0.x*w0 + a0.y*w1 + a0.z*w2 + a0.w*w3
                    + a1.x*w4 + a1.y*w5 + a1.z*w6 + a1.w*w7 + b;
            float sg = 1.0f / (1.0f + __expf(-x));
            int p = parent[i];
            float c = sg * (__half2float(lev16[i]) - __half2float(lev16[p]));
            if (i == 0) stSP(&buf[0], levels[0], N);   // root sentinel p=N
            else        stSP(&buf[i], c, p);
        }
    }
    grid.sync();

    // P2: prefix [0,TPREF): serial chase to root inside the 4 MB prefix (L2-hot,
    // hop targets concentrate exponentially at low indices). Exact, any depth.
    for (int i = tid; i < TPREF; i += nthr) {
        float acc = 0.0f; int p = i;
        while (p < TPREF) { SP w = ldSP(&buf[p]); acc += w.s; p = w.p; }
        yAll[i] = acc;                 // p exited via root sentinel only
        y16[i]  = __float2half(acc);
    }
    grid.sync();

    // P3: [TPREF,N): chase while p >= TPREF (index shrinks ~e x per hop,
    // ~1.2M total hops), then add exact prefix sum. Exact, any depth.
    for (int i = TPREF + tid; i < N; i += nthr) {
        float acc = 0.0f; int p = i;
        while (p >= TPREF && p < N) { SP w = ldSP(&buf[p]); acc += w.s; p = w.p; }
        if (p < TPREF) acc += yAll[p];
        y16[i] = __float2half(acc);
    }
    grid.sync();

    // P4/P5: pixel gather, segmented by node range so each phase's working set
    // is a 2 MB slice of y16 (L2-resident per XCD). Each thread owns 8 pixels
    // in registers across both phases; one coalesced NT write at the end.
    {
        const vi4* pix4 = reinterpret_cast<const vi4*>(pix);
        vf4* out4 = reinterpret_cast<vf4*>(out);
        const int M8 = M >> 3;
        const int nchunk = (M8 + nthr - 1) / nthr;   // uniform across all threads
        for (int c = 0; c < nchunk; ++c) {
            int g = c * nthr + tid;
            bool valid = (g < M8);
            vi4 p0{}, p1{}; vf4 o0{}, o1{};
            if (valid) {
                p0 = __builtin_nontemporal_load(&pix4[2*g]);
                p1 = __builtin_nontemporal_load(&pix4[2*g+1]);
                if (p0.x < SEG) o0.x = __half2float(y16[p0.x]);
                if (p0.y < SEG) o0.y = __half2float(y16[p0.y]);
                if (p0.z < SEG) o0.z = __half2float(y16[p0.z]);
                if (p0.w < SEG) o0.w = __half2float(y16[p0.w]);
                if (p1.x < SEG) o1.x = __half2float(y16[p1.x]);
                if (p1.y < SEG) o1.y = __half2float(y16[p1.y]);
                if (p1.z < SEG) o1.z = __half2float(y16[p1.z]);
                if (p1.w < SEG) o1.w = __half2float(y16[p1.w]);
            }
            grid.sync();               // seg-0 traffic drained machine-wide
            if (valid) {
                if (p0.x >= SEG) o0.x = __half2float(y16[p0.x]);
                if (p0.y >= SEG) o0.y = __half2float(y16[p0.y]);
                if (p0.z >= SEG) o0.z = __half2float(y16[p0.z]);
                if (p0.w >= SEG) o0.w = __half2float(y16[p0.w]);
                if (p1.x >= SEG) o1.x = __half2float(y16[p1.x]);
                if (p1.y >= SEG) o1.y = __half2float(y16[p1.y]);
                if (p1.z >= SEG) o1.z = __half2float(y16[p1.z]);
                if (p1.w >= SEG) o1.w = __half2float(y16[p1.w]);
                __builtin_nontemporal_store(o0, &out4[2*g]);
                __builtin_nontemporal_store(o1, &out4[2*g+1]);
            }
        }
        // tail if M % 8 != 0 (not the case at 2048x2048; uniform, no syncs inside)
        for (int i = (M8 << 3) + tid; i < M; i += nthr)
            out[i] = __half2float(y16[pix[i]]);
    }
}

extern "C" void kernel_launch(void* const* d_in, const int* in_sizes, int n_in,
                              void* d_out, int out_size, void* d_ws, size_t ws_size,
                              hipStream_t stream) {
    const float* attrs  = (const float*)d_in[0];
    const float* weight = (const float*)d_in[1];
    const float* bias   = (const float*)d_in[2];
    const float* levels = (const float*)d_in[3];
    const int*   parent = (const int*)d_in[4];
    const int*   pix    = (const int*)d_in[5];
    float* out = (float*)d_out;

    int N = in_sizes[3];     // 2,000,000 nodes
    int M = out_size;        // H*W pixels

    SP*     buf   = (SP*)d_ws;                  // 16 MB packed {contrib, parent}
    float*  yAll  = (float*)(buf + N);          //  8 MB exact prefix sums (f32)
    __half* y16   = (__half*)(yAll + N);        //  4 MB node outputs (fp16)
    __half* lev16 = (__half*)(y16 + N);         //  4 MB levels (fp16)

    // __launch_bounds__(256,8) caps VGPR at 64 -> 8 blocks/CU; query anyway.
    int nb = 0;
    (void)hipOccupancyMaxActiveBlocksPerMultiprocessor(&nb, k_fused, 256, 0);
    if (nb < 1) nb = 1;
    int grid = nb * 256;                 // 256 CUs on MI355X
    if (grid > 2048) grid = 2048;        // 524288 threads = 1 chunk of 8 pixels each

    void* args[] = {(void*)&attrs, (void*)&weight, (void*)&bias, (void*)&levels,
                    (void*)&parent, (void*)&pix, (void*)&out, (void*)&buf,
                    (void*)&yAll, (void*)&y16, (void*)&lev16,
                    (void*)&N, (void*)&M};
    (void)hipLaunchCooperativeKernel((const void*)k_fused, dim3(grid), dim3(256),
                                     args, 0, stream);
}

// Round 7
// 95.837 us; speedup vs baseline: 12.8499x; 12.8499x over previous
//
#include <hip/hip_runtime.h>
#include <hip/hip_fp16.h>

// Clang native vector types — required by __builtin_nontemporal_* (HIP's
// float4/int4 are classes, which the builtin rejects).
typedef float vf4 __attribute__((ext_vector_type(4)));
typedef int   vi4 __attribute__((ext_vector_type(4)));

// Packed node record: path-segment sum s and jump pointer p in 8 bytes,
// so each random gather touches exactly one cache line.
struct SP { float s; int p; };

__device__ __forceinline__ SP ldSP(const SP* __restrict__ ptr) {
    float2 v = *reinterpret_cast<const float2*>(ptr);
    SP r; r.s = v.x; r.p = __float_as_int(v.y);
    return r;
}
__device__ __forceinline__ void stSP(SP* __restrict__ ptr, float s, int p) {
    float2 v; v.x = s; v.y = __int_as_float(p);
    *reinterpret_cast<float2*>(ptr) = v;
}

// levels -> fp16 table (4 MB, L2-resident) so contrib's random parent-level
// gathers stop missing. f32 source streamed nontemporally.
__global__ void k_lev16(const float* __restrict__ levels,
                        __half* __restrict__ lev, int N) {
    int stride = gridDim.x * blockDim.x;
    int n4 = N >> 2;
    const vf4* l4 = reinterpret_cast<const vf4*>(levels);
    __half2* h2 = reinterpret_cast<__half2*>(lev);
    for (int i = blockIdx.x * blockDim.x + threadIdx.x; i < n4; i += stride) {
        vf4 v = __builtin_nontemporal_load(&l4[i]);
        __half2 h0; h0.x = __float2half(v.x); h0.y = __float2half(v.y);
        __half2 h1; h1.x = __float2half(v.z); h1.y = __float2half(v.w);
        h2[2 * i]     = h0;
        h2[2 * i + 1] = h1;
    }
    for (int i = (n4 << 2) + blockIdx.x * blockDim.x + threadIdx.x; i < N; i += stride)
        lev[i] = __float2half(levels[i]);
}

// contrib[i] = sigmoid(attrs[i]·w + b) * (lev[i] - lev[parent]); root = levels[0]
// with sentinel p=N. attrs/parent are one-shot streams -> nontemporal.
__global__ void k_contrib(const float* __restrict__ attrs,
                          const float* __restrict__ weight,
                          const float* __restrict__ bias,
                          const float* __restrict__ levels,
                          const __half* __restrict__ lev,
                          const int*   __restrict__ parent,
                          SP* __restrict__ buf, int N) {
    float w0 = weight[0], w1 = weight[1], w2 = weight[2], w3 = weight[3];
    float w4 = weight[4], w5 = weight[5], w6 = weight[6], w7 = weight[7];
    float b = bias[0];
    int stride = gridDim.x * blockDim.x;
    const vf4* a4 = reinterpret_cast<const vf4*>(attrs);
    for (int i = blockIdx.x * blockDim.x + threadIdx.x; i < N; i += stride) {
        vf4 a0 = __builtin_nontemporal_load(&a4[2 * (size_t)i]);
        vf4 a1 = __builtin_nontemporal_load(&a4[2 * (size_t)i + 1]);
        float x = a0.x * w0 + a0.y * w1 + a0.z * w2 + a0.w * w3
                + a1.x * w4 + a1.y * w5 + a1.z * w6 + a1.w * w7 + b;
        float sg = 1.0f / (1.0f + __expf(-x));
        int p = __builtin_nontemporal_load(&parent[i]);
        float c = sg * (__half2float(lev[i]) - __half2float(lev[p]));  // lev[p]: L2-hot
        if (i == 0) stSP(&buf[0], levels[0], N);   // root: exact f32 level, sentinel
        else        stSP(&buf[i], c, p);
    }
}

// One ladder level [lo,hi): chase while the chain stays >= lo (parent index
// shrinks ~e x per hop), then add y16 of the already-exact lower levels
// (region <= lo*2 bytes, L2-resident). Bottom level (lo=0) exits only via the
// root sentinel p=N. fp16 rounding chains once per LEVEL (4 levels), not per
// tree edge. Correct for any tree depth.
__global__ void k_level(const SP* __restrict__ buf,
                        __half* __restrict__ y16,
                        int lo, int hi, int N) {
    int i = lo + blockIdx.x * blockDim.x + threadIdx.x;
    if (i >= hi) return;
    float acc = 0.0f;
    int p = i;                       // first gather = coalesced self-read
    while (p >= lo && p < N) {
        SP w = ldSP(&buf[p]);
        acc += w.s;
        p = w.p;
    }
    if (p < lo) acc += __half2float(y16[p]);
    y16[i] = __float2half(acc);
}

// out[pixel] = y16[pixel_node[pixel]]. y16 (4 MB) is the only reused array;
// pix/out streams are nontemporal so they don't evict it from L2.
__global__ void k_gather(const __half* __restrict__ y,
                         const int*   __restrict__ pix,
                         float*       __restrict__ out, int M) {
    int stride = gridDim.x * blockDim.x;
    int M4 = M >> 2;
    const vi4* pix4 = reinterpret_cast<const vi4*>(pix);
    vf4* out4 = reinterpret_cast<vf4*>(out);
    for (int i = blockIdx.x * blockDim.x + threadIdx.x; i < M4; i += stride) {
        vi4 p = __builtin_nontemporal_load(&pix4[i]);
        vf4 o;
        o.x = __half2float(y[p.x]);
        o.y = __half2float(y[p.y]);
        o.z = __half2float(y[p.z]);
        o.w = __half2float(y[p.w]);
        __builtin_nontemporal_store(o, &out4[i]);
    }
    int tid = blockIdx.x * blockDim.x + threadIdx.x;
    for (int i = (M4 << 2) + tid; i < M; i += stride)
        out[i] = __half2float(y[pix[i]]);
}

extern "C" void kernel_launch(void* const* d_in, const int* in_sizes, int n_in,
                              void* d_out, int out_size, void* d_ws, size_t ws_size,
                              hipStream_t stream) {
    const float* attrs  = (const float*)d_in[0];
    const float* weight = (const float*)d_in[1];
    const float* bias   = (const float*)d_in[2];
    const float* levels = (const float*)d_in[3];
    const int*   parent = (const int*)d_in[4];
    const int*   pix    = (const int*)d_in[5];
    float* out = (float*)d_out;

    const int N = in_sizes[3];     // 2,000,000 nodes
    const int M = out_size;        // H*W pixels

    SP*     buf   = (SP*)d_ws;                // 16 MB packed {contrib, parent}
    __half* y16   = (__half*)(buf + N);       //  4 MB node outputs (fp16)
    __half* lev16 = (__half*)(y16 + N);       //  4 MB levels (fp16)

    const int BLK = 256;
    #define CDIV(a,b) (((a)+(b)-1)/(b))

    k_lev16  <<<1024, BLK, 0, stream>>>(levels, lev16, N);
    k_contrib<<<2048, BLK, 0, stream>>>(attrs, weight, bias, levels, lev16, parent, buf, N);

    // Geometric ladder, bottom-up. Ratio-2 top levels keep in-level random
    // hops at ~0.39/node; all below-gathers land in <=2 MB of y16 (L2-hot).
    const int T1 = 32768, T2 = 524288, T3 = 1048576;
    k_level<<<CDIV(T1,      BLK), BLK, 0, stream>>>(buf, y16, 0,  T1, N);
    k_level<<<CDIV(T2 - T1, BLK), BLK, 0, stream>>>(buf, y16, T1, T2, N);
    k_level<<<CDIV(T3 - T2, BLK), BLK, 0, stream>>>(buf, y16, T2, T3, N);
    k_level<<<CDIV(N  - T3, BLK), BLK, 0, stream>>>(buf, y16, T3, N,  N);

    k_gather<<<2048, BLK, 0, stream>>>(y16, pix, out, M);
}